// Round 9
// baseline (933.521 us; speedup 1.0000x reference)
//
#include <hip/hip_runtime.h>
#include <math.h>

typedef __attribute__((ext_vector_type(8))) _Float16 f16x8;
typedef __attribute__((ext_vector_type(4))) _Float16 f16x4;
typedef __attribute__((ext_vector_type(4))) float f32x4;

// ---------------------------------------------------------------------------
// Precision: split-fp16 planes a = ah + al/2048 (al stored x2048) ->
// fp32-grade GEMMs (budget ~2^-20 rel; pos/|pos| amplifies ~1e4).
//
// Round 9:
//  (1) msc stored PLANE-BLOCKED fp32: 12 planes of Mr x 16 floats (3.2 MB
//      < 4 MiB per-XCD L2). Aggregation is chunk-major: whole GPU works one
//      plane at a time; random gathers become L2 hits; the 8x38 MB fill
//      floor becomes streaming (explicit coalesced prefetch stripe/block).
//      Fixes round-4's two failures (line waste + L2 overflow).
//  (2) Dispatch-count cuts: prep = count+convert_x+pack_b in one kernel;
//      tail = p2-GEMM + rb-GEMM + finalize in one kernel (kills 77 MB of
//      p2/rb round-trip too). 25 -> 17 dispatches.
//  GEMM structure unchanged from r8 (ROWS=64, all-A staged, one barrier).
// ---------------------------------------------------------------------------

// ------------------------- graph setup -------------------------------------
__global__ void scan1_kernel(const int* __restrict__ cnt, int M,
                             int* __restrict__ rowptr, int* __restrict__ bsum,
                             float* __restrict__ dinv) {
    __shared__ int s[256];
    int t = threadIdx.x;
    int i = blockIdx.x * 256 + t;
    int v = (i < M) ? cnt[i] : 0;
    s[t] = v; __syncthreads();
    for (int o = 1; o < 256; o <<= 1) {
        int x = (t >= o) ? s[t - o] : 0;
        __syncthreads();
        s[t] += x;
        __syncthreads();
    }
    if (i < M) {
        rowptr[i] = s[t] - v;
        dinv[i] = rsqrtf((float)v + 1.0f);  // deg = in-deg + self-loop
    }
    if (t == 255) bsum[blockIdx.x] = s[255];
}

__global__ void scan2_kernel(const int* __restrict__ bsum, int nb, int* __restrict__ boff) {
    __shared__ int s[256];
    int t = threadIdx.x;
    int v = (t < nb) ? bsum[t] : 0;
    s[t] = v; __syncthreads();
    for (int o = 1; o < 256; o <<= 1) {
        int x = (t >= o) ? s[t - o] : 0;
        __syncthreads();
        s[t] += x;
        __syncthreads();
    }
    if (t < nb) boff[t] = s[t] - v;
}

__global__ void scan3_kernel(int* __restrict__ rowptr, int M, int E, const int* __restrict__ boff) {
    int i = blockIdx.x * 256 + threadIdx.x;
    if (i < M) rowptr[i] += boff[blockIdx.x];
    if (i == M) rowptr[M] = E;
}

__global__ void fill_kernel(const int* __restrict__ src, const int* __restrict__ dst, int E,
                            const int* __restrict__ rowptr, int* __restrict__ cursor,
                            int* __restrict__ csr) {
    int i = blockIdx.x * blockDim.x + threadIdx.x;
    if (i < E) {
        int d = dst[i];
        int slot = atomicAdd(&cursor[d], 1);
        csr[rowptr[d] + slot] = src[i];
    }
}

// ---------------- fused prep: count + convert_x + pack_b --------------------
struct WSeg { const float* src; _Float16* dh; _Float16* dl; int K; int N; };
struct WSegs { WSeg s[8]; };

__global__ void prep_kernel(const int* __restrict__ dst, int E, int* __restrict__ cnt,
                            const float* __restrict__ x, _Float16* __restrict__ xp,
                            int M, int xchunks, WSegs segs,
                            int nCount, int nConv) {
    int b = blockIdx.x;
    if (b < nCount) {
        int i = b * 256 + threadIdx.x;
        if (i < E) atomicAdd(&cnt[dst[i]], 1);
        return;
    }
    b -= nCount;
    if (b < nConv) {
        // x -> block-packed split planes (4 slabs), one 16-B chunk per thread
        int g = b * 256 + threadIdx.x;
        if (g >= xchunks) return;
        int p = g & 7;
        int t1 = g >> 3;
        int r = t1 & 31;
        int t2 = t1 >> 5;
        int s = t2 & 3;
        int rb = t2 >> 2;
        int c = p ^ (r & 7);
        int node = rb * 32 + r;
        int k = s * 32 + (c & 3) * 8;
        f16x8 o = {};
        if (node < M) {
            const float* xr = x + (size_t)node * 128 + k;
#pragma unroll
            for (int j = 0; j < 8; ++j) {
                float v = xr[j];
                _Float16 hi = (_Float16)v;
                o[j] = (c < 4) ? hi : (_Float16)((v - (float)hi) * 2048.f);
            }
        }
        reinterpret_cast<f16x8*>(xp)[g] = o;
        return;
    }
    b -= nConv;
    // pack_b: frag-major WT planes, flat i = ((s*G+g)*64+l)*8+j
    WSeg sg = segs.s[b / 144];
    int i = (b % 144) * 256 + threadIdx.x;
    if (i >= sg.K * sg.N) return;
    int G = sg.N >> 4;
    int s = i / (G * 512);
    int r = i - s * (G * 512);
    int g = r >> 9;
    int r2 = r & 511;
    int l = r2 >> 3, j = r2 & 7;
    int n = g * 16 + (l & 15);
    int k = s * 32 + (l >> 4) * 8 + j;
    float w = sg.src[(size_t)k * sg.N + n];
    _Float16 hi = (_Float16)w;
    sg.dh[i] = hi;
    sg.dl[i] = (_Float16)((w - (float)hi) * 2048.f);
}

// --------------------- global->LDS 16B helper -------------------------------
__device__ __forceinline__ void gload_lds16(const _Float16* src, char* dst_wavebase) {
#if __has_builtin(__builtin_amdgcn_global_load_lds)
    __builtin_amdgcn_global_load_lds(
        (const __attribute__((address_space(1))) void*)src,
        (__attribute__((address_space(3))) void*)dst_wavebase, 16, 0, 0);
#else
    *reinterpret_cast<f16x8*>(dst_wavebase + (threadIdx.x & 63) * 16) =
        *reinterpret_cast<const f16x8*>(src);
#endif
}

// ---------------------------------------------------------------------------
// Split-fp16 MFMA GEMM (r8 structure): ROWS=64, all-A staged, one barrier,
// B frag-major from global. NN=192 only: MT=4, wave w -> cols [w*48,+48).
// OM bit1: block-packed split out Cp. OM bit2: fp32 PLANE-BLOCKED out Cf
// (plane = col/16, offset = (plane*Mr + row)*16 + col%16). rowscale last.
// ---------------------------------------------------------------------------
template <int KK, int NN, int ACT, int OM>
__global__ __launch_bounds__(256, 2) void mfma_gemm(
    const _Float16* __restrict__ Ap,
    const _Float16* __restrict__ Bph, const _Float16* __restrict__ Bpl,
    const float* __restrict__ bias, const float* __restrict__ rowscale,
    float* __restrict__ Cf, _Float16* __restrict__ Cp, int M, int Mr) {
    constexpr int NS = KK / 32;
    constexpr int G = NN / 16;
    constexpr int MT = 4;
    constexpr int NSO = NN / 32;
    __shared__ __align__(16) char smem[NS * 8192];

    const int tid = threadIdx.x;
    const int wave = tid >> 6, lane = tid & 63;
    const int quad = lane >> 4, l16 = lane & 15;
    const int n0 = wave * 48;
    const int g0 = n0 >> 4;
    const int row0 = blockIdx.x * 64;
    const int wb = (tid & ~63) * 16;

#pragma unroll
    for (int s = 0; s < NS; ++s)
#pragma unroll
        for (int half = 0; half < 2; ++half) {
            const _Float16* src =
                Ap + ((size_t)(2 * blockIdx.x + half) * NS + s) * 2048 + tid * 8;
            gload_lds16(src, smem + (s * 2 + half) * 4096 + wb);
        }

    f32x4 acc[MT][3], acc2[MT][3];
#pragma unroll
    for (int mt = 0; mt < MT; ++mt)
#pragma unroll
        for (int nt = 0; nt < 3; ++nt) {
            acc[mt][nt] = (f32x4){0.f, 0.f, 0.f, 0.f};
            acc2[mt][nt] = (f32x4){0.f, 0.f, 0.f, 0.f};
        }

    __syncthreads();  // the ONLY barrier

#pragma unroll
    for (int s = 0; s < NS; ++s) {
        f16x8 bh[3], bl[3];
#pragma unroll
        for (int nt = 0; nt < 3; ++nt) {
            size_t o = ((size_t)(s * G + g0 + nt) * 64 + lane) * 8;
            bh[nt] = *reinterpret_cast<const f16x8*>(Bph + o);
            bl[nt] = *reinterpret_cast<const f16x8*>(Bpl + o);
        }
        const char* As = smem + s * 8192;
        f16x8 ah[MT], al[MT];
#pragma unroll
        for (int mt = 0; mt < MT; ++mt) {
            int R = mt * 16 + l16;
            int ph = quad ^ (R & 7);
            const char* rbase = As + (R >> 5) * 4096 + (R & 31) * 128;
            ah[mt] = *reinterpret_cast<const f16x8*>(rbase + ph * 16);
            al[mt] = *reinterpret_cast<const f16x8*>(rbase + (ph ^ 4) * 16);
        }
#pragma unroll
        for (int mt = 0; mt < MT; ++mt)
#pragma unroll
            for (int nt = 0; nt < 3; ++nt) {
                acc[mt][nt] = __builtin_amdgcn_mfma_f32_16x16x32_f16(ah[mt], bh[nt], acc[mt][nt], 0, 0, 0);
                acc2[mt][nt] = __builtin_amdgcn_mfma_f32_16x16x32_f16(ah[mt], bl[nt], acc2[mt][nt], 0, 0, 0);
                acc2[mt][nt] = __builtin_amdgcn_mfma_f32_16x16x32_f16(al[mt], bh[nt], acc2[mt][nt], 0, 0, 0);
            }
    }

    // epilogue: C/D layout col=lane&15, row=quad*4+reg
    float bv[3];
#pragma unroll
    for (int nt = 0; nt < 3; ++nt) bv[nt] = bias ? bias[n0 + nt * 16 + l16] : 0.f;
#pragma unroll
    for (int mt = 0; mt < MT; ++mt)
#pragma unroll
        for (int i = 0; i < 4; ++i) {
            int row = row0 + mt * 16 + quad * 4 + i;
            if (row < M) {
                float rs = rowscale ? rowscale[row] : 1.f;
#pragma unroll
                for (int nt = 0; nt < 3; ++nt) {
                    int col = n0 + nt * 16 + l16;
                    float v = acc[mt][nt][i] + acc2[mt][nt][i] * (1.f / 2048.f) + bv[nt];
                    if (ACT == 1) v = fmaxf(v, 0.f);
                    v *= rs;
                    if (OM & 4)
                        Cf[((size_t)(col >> 4) * Mr + row) * 16 + (col & 15)] = v;
                    if (OM & 2) {
                        _Float16 hi = (_Float16)v;
                        _Float16 lo = (_Float16)((v - (float)hi) * 2048.f);
                        int r = row & 31;
                        int os = col >> 5, oc = (col >> 3) & 3, j = col & 7;
                        size_t base = ((size_t)((row >> 5) * NSO + os) * 32 + r) * 64;
                        int ph2 = oc ^ (r & 7);
                        Cp[base + ph2 * 8 + j] = hi;
                        Cp[base + (ph2 ^ 4) * 8 + j] = lo;
                    }
                }
            }
        }
}

// ---------------------------------------------------------------------------
// Chunk-major plane-blocked fp32 aggregation. Grid = 12*NG, chunk = bid/NG.
// Per chunk: msc plane (Mr x 16 floats, 3.2 MB) is L2-resident per XCD;
// each block prefetches a coalesced stripe (streams the fill), then 64
// nodes x 4 lanes gather float4s (L2 hits). h (block-packed split-fp16)
// updated on the chunk's 16-feature slice.
// ---------------------------------------------------------------------------
__global__ __launch_bounds__(256) void aggregate_kernel(
    const float* __restrict__ msc, const int* __restrict__ csr,
    const int* __restrict__ rowptr, const float* __restrict__ dinv,
    const float* __restrict__ bias, _Float16* __restrict__ h,
    int M, int Mr, int NG) {
    const int chunk = blockIdx.x / NG;
    const int g = blockIdx.x - chunk * NG;
    const int t = threadIdx.x;
    const float4* pl = reinterpret_cast<const float4*>(msc) + (size_t)chunk * Mr * 4;

    // streaming prefetch: contiguous stripe of the plane per block
    {
        const int nf4 = Mr * 4;
        const int q = (nf4 + NG - 1) / NG;  // ~257
        float pf = 0.f;
        for (int it = 0; it < (q + 255) / 256; ++it) {
            int i = g * q + it * 256 + t;
            if (i < nf4 && i < (g + 1) * q) {
                float4 v = pl[i];
                pf += v.x + v.y + v.z + v.w;
            }
        }
        asm volatile("" : : "v"(pf));  // keep the loads
    }

    const int node = g * 64 + (t >> 2);
    if (node >= M) return;
    const int cl = t & 3;

    float4 a0 = pl[(size_t)node * 4 + cl];  // self-loop (already * dinv[node])
    float4 a1 = make_float4(0.f, 0.f, 0.f, 0.f);
    const int beg = rowptr[node], end = rowptr[node + 1];
    int e = beg;
    for (; e + 1 < end; e += 2) {
        int s0 = csr[e], s1 = csr[e + 1];
        float4 v0 = pl[(size_t)s0 * 4 + cl];
        float4 v1 = pl[(size_t)s1 * 4 + cl];
        a0.x += v0.x; a0.y += v0.y; a0.z += v0.z; a0.w += v0.w;
        a1.x += v1.x; a1.y += v1.y; a1.z += v1.z; a1.w += v1.w;
    }
    if (e < end) {
        float4 v = pl[(size_t)csr[e] * 4 + cl];
        a0.x += v.x; a0.y += v.y; a0.z += v.z; a0.w += v.w;
    }
    a0.x += a1.x; a0.y += a1.y; a0.z += a1.z; a0.w += a1.w;

    const float dn = dinv[node];
    const float4 b = reinterpret_cast<const float4*>(bias)[chunk * 4 + cl];

    // packed-h granule for features f0 = chunk*16 + cl*4
    int f0 = chunk * 16 + cl * 4;
    int s = f0 >> 5, c = (f0 >> 3) & 3, jh = (f0 >> 2) & 1;
    int r = node & 31;
    size_t pbase = ((size_t)((node >> 5) * 6 + s) * 32 + r) * 64;
    int ph = c ^ (r & 7);
    f16x4* hp = reinterpret_cast<f16x4*>(h + pbase + ph * 8 + jh * 4);
    f16x4* lp = reinterpret_cast<f16x4*>(h + pbase + (ph ^ 4) * 8 + jh * 4);
    f16x4 hh = *hp, hl = *lp;
    float4 hv;
    hv.x = (float)hh[0] + (float)hl[0] * (1.f / 2048.f) + fmaxf(a0.x * dn + b.x, 0.f);
    hv.y = (float)hh[1] + (float)hl[1] * (1.f / 2048.f) + fmaxf(a0.y * dn + b.y, 0.f);
    hv.z = (float)hh[2] + (float)hl[2] * (1.f / 2048.f) + fmaxf(a0.z * dn + b.z, 0.f);
    hv.w = (float)hh[3] + (float)hl[3] * (1.f / 2048.f) + fmaxf(a0.w * dn + b.w, 0.f);
    f16x4 nh = {(_Float16)hv.x, (_Float16)hv.y, (_Float16)hv.z, (_Float16)hv.w};
    f16x4 nl = {(_Float16)((hv.x - (float)nh[0]) * 2048.f),
                (_Float16)((hv.y - (float)nh[1]) * 2048.f),
                (_Float16)((hv.z - (float)nh[2]) * 2048.f),
                (_Float16)((hv.w - (float)nh[3]) * 2048.f)};
    *hp = nh;
    *lp = nl;
}

// ---------------------------------------------------------------------------
// Fused tail: p2 = relu(p1@Wp2+b), r = relu(h@Wr1+b) (both NN=96 split-fp16
// MFMA from staged 32-row tiles), then per-row: pos = p2·Wp3+bp3,
// rad = sigmoid(r·Wr2+br2), out = pos/(|pos|+1e-8)*rad. One dispatch,
// no p2/r round trip. 256 thr = 4 waves; wave w: rows [(w>>1)*16,+16),
// cols [(w&1)*48,+48).
// ---------------------------------------------------------------------------
__global__ __launch_bounds__(256, 2) void tail_kernel(
    const _Float16* __restrict__ p1p, const _Float16* __restrict__ hp_,
    const _Float16* __restrict__ W2h, const _Float16* __restrict__ W2l,
    const _Float16* __restrict__ Wrh, const _Float16* __restrict__ Wrl,
    const float* __restrict__ bp2, const float* __restrict__ br1,
    const float* __restrict__ Wp3, const float* __restrict__ bp3,
    const float* __restrict__ Wr2, const float* __restrict__ br2,
    float* __restrict__ out, int M) {
    __shared__ __align__(16) char smem[49152];  // 6x4KB p1 + 6x4KB h; reused for tiles
    const int tid = threadIdx.x;
    const int wave = tid >> 6, lane = tid & 63;
    const int quad = lane >> 4, l16 = lane & 15;
    const int m0 = (wave >> 1) * 16;
    const int n0 = (wave & 1) * 48;
    const int g0 = n0 >> 4;  // G = 6
    const int row0 = blockIdx.x * 32;
    const int wb = (tid & ~63) * 16;

#pragma unroll
    for (int s = 0; s < 6; ++s) {
        gload_lds16(p1p + ((size_t)blockIdx.x * 6 + s) * 2048 + tid * 8,
                    smem + s * 4096 + wb);
        gload_lds16(hp_ + ((size_t)blockIdx.x * 6 + s) * 2048 + tid * 8,
                    smem + 24576 + s * 4096 + wb);
    }

    f32x4 aP[3], aP2[3], aR[3], aR2[3];
#pragma unroll
    for (int nt = 0; nt < 3; ++nt) {
        aP[nt] = (f32x4){0.f, 0.f, 0.f, 0.f};
        aP2[nt] = aP[nt]; aR[nt] = aP[nt]; aR2[nt] = aP[nt];
    }
    __syncthreads();

#pragma unroll
    for (int s = 0; s < 6; ++s) {
        f16x8 b2h[3], b2l[3], brh[3], brl[3];
#pragma unroll
        for (int nt = 0; nt < 3; ++nt) {
            size_t o = ((size_t)(s * 6 + g0 + nt) * 64 + lane) * 8;
            b2h[nt] = *reinterpret_cast<const f16x8*>(W2h + o);
            b2l[nt] = *reinterpret_cast<const f16x8*>(W2l + o);
            brh[nt] = *reinterpret_cast<const f16x8*>(Wrh + o);
            brl[nt] = *reinterpret_cast<const f16x8*>(Wrl + o);
        }
        int R = m0 + l16;
        int ph = quad ^ (R & 7);
        const char* r1 = smem + s * 4096 + R * 128;
        const char* r2 = smem + 24576 + s * 4096 + R * 128;
        f16x8 p1h = *reinterpret_cast<const f16x8*>(r1 + ph * 16);
        f16x8 p1l = *reinterpret_cast<const f16x8*>(r1 + (ph ^ 4) * 16);
        f16x8 hh = *reinterpret_cast<const f16x8*>(r2 + ph * 16);
        f16x8 hl = *reinterpret_cast<const f16x8*>(r2 + (ph ^ 4) * 16);
#pragma unroll
        for (int nt = 0; nt < 3; ++nt) {
            aP[nt] = __builtin_amdgcn_mfma_f32_16x16x32_f16(p1h, b2h[nt], aP[nt], 0, 0, 0);
            aP2[nt] = __builtin_amdgcn_mfma_f32_16x16x32_f16(p1h, b2l[nt], aP2[nt], 0, 0, 0);
            aP2[nt] = __builtin_amdgcn_mfma_f32_16x16x32_f16(p1l, b2h[nt], aP2[nt], 0, 0, 0);
            aR[nt] = __builtin_amdgcn_mfma_f32_16x16x32_f16(hh, brh[nt], aR[nt], 0, 0, 0);
            aR2[nt] = __builtin_amdgcn_mfma_f32_16x16x32_f16(hh, brl[nt], aR2[nt], 0, 0, 0);
            aR2[nt] = __builtin_amdgcn_mfma_f32_16x16x32_f16(hl, brh[nt], aR2[nt], 0, 0, 0);
        }
    }

    __syncthreads();  // staging data dead; reuse smem for tiles
    float* p2t = (float*)smem;             // [32][96]
    float* rbt = (float*)(smem + 12288);   // [32][96]
#pragma unroll
    for (int i = 0; i < 4; ++i) {
        int row = m0 + quad * 4 + i;  // 0..31
#pragma unroll
        for (int nt = 0; nt < 3; ++nt) {
            int col = n0 + nt * 16 + l16;
            float v2 = aP[nt][i] + aP2[nt][i] * (1.f / 2048.f) + bp2[col];
            float vr = aR[nt][i] + aR2[nt][i] * (1.f / 2048.f) + br1[col];
            p2t[row * 96 + col] = fmaxf(v2, 0.f);
            rbt[row * 96 + col] = fmaxf(vr, 0.f);
        }
    }
    __syncthreads();

    if (tid < 32) {
        int row = row0 + tid;
        if (row < M) {
            float a0 = 0.f, a1 = 0.f, rr = 0.f;
            const float* p = p2t + tid * 96;
            const float* r = rbt + tid * 96;
#pragma unroll
            for (int j = 0; j < 96; ++j) {
                a0 += p[j] * Wp3[j * 2 + 0];
                a1 += p[j] * Wp3[j * 2 + 1];
                rr += r[j] * Wr2[j];
            }
            a0 += bp3[0];
            a1 += bp3[1];
            rr += br2[0];
            float radius = 1.f / (1.f + expf(-rr));
            float nrm = sqrtf(a0 * a0 + a1 * a1) + 1e-8f;
            float sc = radius / nrm;
            out[(size_t)row * 2 + 0] = a0 * sc;
            out[(size_t)row * 2 + 1] = a1 * sc;
        }
    }
}

extern "C" void kernel_launch(void* const* d_in, const int* in_sizes, int n_in,
                              void* d_out, int out_size, void* d_ws, size_t ws_size,
                              hipStream_t stream) {
    const float* x     = (const float*)d_in[0];
    const int*   ei    = (const int*)d_in[1];
    const float* Wp    = (const float*)d_in[2];
    const float* bp    = (const float*)d_in[3];
    const float* convW = (const float*)d_in[4];
    const float* convB = (const float*)d_in[5];
    const float* Wp1   = (const float*)d_in[6];
    const float* bp1   = (const float*)d_in[7];
    const float* Wp2   = (const float*)d_in[8];
    const float* bp2   = (const float*)d_in[9];
    const float* Wp3   = (const float*)d_in[10];
    const float* bp3   = (const float*)d_in[11];
    const float* Wr1   = (const float*)d_in[12];
    const float* br1   = (const float*)d_in[13];
    const float* Wr2   = (const float*)d_in[14];
    const float* br2   = (const float*)d_in[15];
    float* out = (float*)d_out;

    const int M = in_sizes[0] / 128;  // 50000
    const int E = in_sizes[1] / 2;    // 800000
    const int* srcI = ei;
    const int* dstI = ei + E;
    const int RB64 = (M + 63) / 64;   // 782
    const int RBp  = RB64 * 2;        // 1564 32-row pages
    const int Mr   = RBp * 32;        // 50048 padded rows

    char* w = (char*)d_ws;
    size_t off = 0;
    auto alloc = [&](size_t b) { size_t o = off; off += (b + 255) & ~(size_t)255; return o; };
    float*    msc  = (float*)(w + alloc((size_t)Mr * 192 * 4));      // plane-blocked; reused as p1 packed
    _Float16* hpk  = (_Float16*)(w + alloc((size_t)RBp * 6 * 4096)); // h packed
    _Float16* xpk  = (_Float16*)(w + alloc((size_t)RBp * 4 * 4096)); // x packed
    _Float16* WpPh  = (_Float16*)(w + alloc((size_t)128 * 192 * 2));
    _Float16* WpPl  = (_Float16*)(w + alloc((size_t)128 * 192 * 2));
    _Float16* cWPh  = (_Float16*)(w + alloc((size_t)4 * 192 * 192 * 2));
    _Float16* cWPl  = (_Float16*)(w + alloc((size_t)4 * 192 * 192 * 2));
    _Float16* Wp1Ph = (_Float16*)(w + alloc((size_t)192 * 192 * 2));
    _Float16* Wp1Pl = (_Float16*)(w + alloc((size_t)192 * 192 * 2));
    _Float16* Wp2Ph = (_Float16*)(w + alloc((size_t)192 * 96 * 2));
    _Float16* Wp2Pl = (_Float16*)(w + alloc((size_t)192 * 96 * 2));
    _Float16* Wr1Ph = (_Float16*)(w + alloc((size_t)192 * 96 * 2));
    _Float16* Wr1Pl = (_Float16*)(w + alloc((size_t)192 * 96 * 2));
    int*      cnt    = (int*)(w + alloc((size_t)M * 4));
    int*      cursor = (int*)(w + alloc((size_t)M * 4));
    float*    dinv   = (float*)(w + alloc((size_t)M * 4));
    int*      rowptr = (int*)(w + alloc((size_t)(M + 1) * 4));
    int*      csr    = (int*)(w + alloc((size_t)(E + 64) * 4));
    int*      bsum   = (int*)(w + alloc(256 * 4));
    int*      boff   = (int*)(w + alloc(256 * 4));

    _Float16* p1pk = (_Float16*)msc;  // alias: msc dead after last aggregate

    hipMemsetAsync(cnt, 0, (size_t)((char*)cursor - (char*)cnt) + (size_t)M * 4, stream);

    // fused prep: count + convert_x + pack_b
    const int xchunks = RBp * 4 * 256;
    const int nCount = (E + 255) / 256;        // 3125
    const int nConv  = (xchunks + 255) / 256;  // 6256
    WSegs segs;
    segs.s[0] = {Wp, WpPh, WpPl, 128, 192};
    segs.s[1] = {convW + 0 * 192 * 192, cWPh + 0 * 192 * 192, cWPl + 0 * 192 * 192, 192, 192};
    segs.s[2] = {convW + 1 * 192 * 192, cWPh + 1 * 192 * 192, cWPl + 1 * 192 * 192, 192, 192};
    segs.s[3] = {convW + 2 * 192 * 192, cWPh + 2 * 192 * 192, cWPl + 2 * 192 * 192, 192, 192};
    segs.s[4] = {convW + 3 * 192 * 192, cWPh + 3 * 192 * 192, cWPl + 3 * 192 * 192, 192, 192};
    segs.s[5] = {Wp1, Wp1Ph, Wp1Pl, 192, 192};
    segs.s[6] = {Wp2, Wp2Ph, Wp2Pl, 192, 96};
    segs.s[7] = {Wr1, Wr1Ph, Wr1Pl, 192, 96};
    prep_kernel<<<nCount + nConv + 8 * 144, 256, 0, stream>>>(
        dstI, E, cnt, x, xpk, M, xchunks, segs, nCount, nConv);

    int nb = (M + 255) / 256;
    scan1_kernel<<<nb, 256, 0, stream>>>(cnt, M, rowptr, bsum, dinv);
    scan2_kernel<<<1, 256, 0, stream>>>(bsum, nb, boff);
    scan3_kernel<<<(M + 256) / 256, 256, 0, stream>>>(rowptr, M, E, boff);
    fill_kernel<<<(E + 255) / 256, 256, 0, stream>>>(srcI, dstI, E, rowptr, cursor, csr);

    const int NG = RB64;  // 782 node-groups of 64

    // h = x @ Wp + bp -> packed planes
    mfma_gemm<128, 192, 0, 2><<<RB64, 256, 0, stream>>>(
        xpk, WpPh, WpPl, bp, nullptr, nullptr, hpk, M, Mr);
    // 4 GCN layers: msc (plane-blocked) = (h@W)*dinv; chunk-major aggregate
    for (int i = 0; i < 4; i++) {
        mfma_gemm<192, 192, 0, 4><<<RB64, 256, 0, stream>>>(
            hpk, cWPh + (size_t)i * 192 * 192, cWPl + (size_t)i * 192 * 192,
            nullptr, dinv, msc, nullptr, M, Mr);
        aggregate_kernel<<<12 * NG, 256, 0, stream>>>(
            msc, csr, rowptr, dinv, convB + (size_t)i * 192, hpk, M, Mr, NG);
    }
    // p1 = relu(h @ Wp1 + bp1) -> packed (aliases msc)
    mfma_gemm<192, 192, 1, 2><<<RB64, 256, 0, stream>>>(
        hpk, Wp1Ph, Wp1Pl, bp1, nullptr, nullptr, p1pk, M, Mr);
    // fused p2/r GEMMs + finalize
    tail_kernel<<<RBp, 256, 0, stream>>>(
        p1pk, hpk, Wp2Ph, Wp2Pl, Wr1Ph, Wr1Pl, bp2, br1,
        Wp3, bp3, Wr2, br2, out, M);
}

// Round 10
// 729.274 us; speedup vs baseline: 1.2801x; 1.2801x over previous
//
#include <hip/hip_runtime.h>
#include <math.h>

typedef __attribute__((ext_vector_type(8))) _Float16 f16x8;
typedef __attribute__((ext_vector_type(4))) _Float16 f16x4;
typedef __attribute__((ext_vector_type(4))) float f32x4;

// ---------------------------------------------------------------------------
// Precision: split-fp16 planes a = ah + al/2048 (al stored x2048) ->
// fp32-grade GEMMs (budget ~2^-20 rel; pos/|pos| amplifies ~1e4).
// Aggregation fp32 whole-row (94 us / 311 MB = 8 XCD x 38.4 MB: the floor).
//
// Round 10 GEMM: NO LDS, NO barriers. Waves load A-frags / B-frags straight
// from global. Packed layout makes every frag load sector-perfect:
//   A page (32 rows x 32 k x 2 planes = 4 KB): chunk16B(r,c) at
//   r*128 + (c^(r&7))*16; a wave's frag = 64 lanes x 16 B covering whole
//   64-B sectors (4 lanes/sector). B frag-major: 64x16 B contiguous 1 KB.
// A (24 KB/block) L1-resident across 4 waves; B (147 KB) L2-hot.
// launch_bounds(256,4): ~16 waves/CU of independent streams hide latency.
// This kills the stage->barrier->compute serialization that pinned r5-r9
// at ~55 us/GEMM regardless of structure.
// ---------------------------------------------------------------------------

// ------------------------- graph setup -------------------------------------
__global__ void scan1_kernel(const int* __restrict__ cnt, int M,
                             int* __restrict__ rowptr, int* __restrict__ bsum,
                             float* __restrict__ dinv) {
    __shared__ int s[256];
    int t = threadIdx.x;
    int i = blockIdx.x * 256 + t;
    int v = (i < M) ? cnt[i] : 0;
    s[t] = v; __syncthreads();
    for (int o = 1; o < 256; o <<= 1) {
        int x = (t >= o) ? s[t - o] : 0;
        __syncthreads();
        s[t] += x;
        __syncthreads();
    }
    if (i < M) {
        rowptr[i] = s[t] - v;
        dinv[i] = rsqrtf((float)v + 1.0f);  // deg = in-deg + self-loop
    }
    if (t == 255) bsum[blockIdx.x] = s[255];
}

__global__ void scan2_kernel(const int* __restrict__ bsum, int nb, int* __restrict__ boff) {
    __shared__ int s[256];
    int t = threadIdx.x;
    int v = (t < nb) ? bsum[t] : 0;
    s[t] = v; __syncthreads();
    for (int o = 1; o < 256; o <<= 1) {
        int x = (t >= o) ? s[t - o] : 0;
        __syncthreads();
        s[t] += x;
        __syncthreads();
    }
    if (t < nb) boff[t] = s[t] - v;
}

__global__ void scan3_kernel(int* __restrict__ rowptr, int M, int E, const int* __restrict__ boff) {
    int i = blockIdx.x * 256 + threadIdx.x;
    if (i < M) rowptr[i] += boff[blockIdx.x];
    if (i == M) rowptr[M] = E;
}

__global__ void fill_kernel(const int* __restrict__ src, const int* __restrict__ dst, int E,
                            const int* __restrict__ rowptr, int* __restrict__ cursor,
                            int* __restrict__ csr) {
    int i = blockIdx.x * blockDim.x + threadIdx.x;
    if (i < E) {
        int d = dst[i];
        int slot = atomicAdd(&cursor[d], 1);
        csr[rowptr[d] + slot] = src[i];
    }
}

// ---------------- fused prep: count + convert_x + pack_b --------------------
struct WSeg { const float* src; _Float16* dh; _Float16* dl; int K; int N; };
struct WSegs { WSeg s[8]; };

__global__ void prep_kernel(const int* __restrict__ dst, int E, int* __restrict__ cnt,
                            const float* __restrict__ x, _Float16* __restrict__ xp,
                            int M, int xchunks, WSegs segs,
                            int nCount, int nConv) {
    int b = blockIdx.x;
    if (b < nCount) {
        int i = b * 256 + threadIdx.x;
        if (i < E) atomicAdd(&cnt[dst[i]], 1);
        return;
    }
    b -= nCount;
    if (b < nConv) {
        // x -> block-packed split planes (4 slabs), one 16-B chunk per thread
        int g = b * 256 + threadIdx.x;
        if (g >= xchunks) return;
        int p = g & 7;
        int t1 = g >> 3;
        int r = t1 & 31;
        int t2 = t1 >> 5;
        int s = t2 & 3;
        int rb = t2 >> 2;
        int c = p ^ (r & 7);
        int node = rb * 32 + r;
        int k = s * 32 + (c & 3) * 8;
        f16x8 o = {};
        if (node < M) {
            const float* xr = x + (size_t)node * 128 + k;
#pragma unroll
            for (int j = 0; j < 8; ++j) {
                float v = xr[j];
                _Float16 hi = (_Float16)v;
                o[j] = (c < 4) ? hi : (_Float16)((v - (float)hi) * 2048.f);
            }
        }
        reinterpret_cast<f16x8*>(xp)[g] = o;
        return;
    }
    b -= nConv;
    // pack_b: frag-major WT planes, flat i = ((s*G+g)*64+l)*8+j
    WSeg sg = segs.s[b / 144];
    int i = (b % 144) * 256 + threadIdx.x;
    if (i >= sg.K * sg.N) return;
    int G = sg.N >> 4;
    int s = i / (G * 512);
    int r = i - s * (G * 512);
    int g = r >> 9;
    int r2 = r & 511;
    int l = r2 >> 3, j = r2 & 7;
    int n = g * 16 + (l & 15);
    int k = s * 32 + (l >> 4) * 8 + j;
    float w = sg.src[(size_t)k * sg.N + n];
    _Float16 hi = (_Float16)w;
    sg.dh[i] = hi;
    sg.dl[i] = (_Float16)((w - (float)hi) * 2048.f);
}

// ---------------------------------------------------------------------------
// Barrier-free LDS-free split-fp16 MFMA GEMM. 256 thr = 4 waves, 32 rows.
// Wave w -> cols [w*48,+48) (NN=192). Per slab per wave: 4 A-frag + 6 B-frag
// direct global loads (sector-coalesced), 18 MFMA. Fully unrolled; compiler
// pipelines with plain vmcnt; no s_barrier anywhere.
// OM bit0: fp32 row-major Cf. OM bit1: block-packed split Cp. rowscale last.
// ---------------------------------------------------------------------------
template <int KK, int NN, int ACT, int OM>
__global__ __launch_bounds__(256, 4) void mfma_gemm(
    const _Float16* __restrict__ Ap,
    const _Float16* __restrict__ Bph, const _Float16* __restrict__ Bpl,
    const float* __restrict__ bias, const float* __restrict__ rowscale,
    float* __restrict__ Cf, _Float16* __restrict__ Cp, int M) {
    constexpr int NS = KK / 32;
    constexpr int G = NN / 16;
    constexpr int MT = 2;
    constexpr int NSO = NN / 32;

    const int tid = threadIdx.x;
    const int wave = tid >> 6, lane = tid & 63;
    const int quad = lane >> 4, l16 = lane & 15;
    const int n0 = wave * 48;
    const int g0 = n0 >> 4;
    const int row0 = blockIdx.x * 32;
    const _Float16* page0 = Ap + (size_t)blockIdx.x * NS * 2048;

    f32x4 acc[MT][3], acc2[MT][3];
#pragma unroll
    for (int mt = 0; mt < MT; ++mt)
#pragma unroll
        for (int nt = 0; nt < 3; ++nt) {
            acc[mt][nt] = (f32x4){0.f, 0.f, 0.f, 0.f};
            acc2[mt][nt] = (f32x4){0.f, 0.f, 0.f, 0.f};
        }

#pragma unroll
    for (int s = 0; s < NS; ++s) {
        const _Float16* pg = page0 + s * 2048;
        f16x8 ah[MT], al[MT];
#pragma unroll
        for (int mt = 0; mt < MT; ++mt) {
            int R = mt * 16 + l16;
            int ph = quad ^ (R & 7);
            ah[mt] = *reinterpret_cast<const f16x8*>(pg + R * 64 + ph * 8);
            al[mt] = *reinterpret_cast<const f16x8*>(pg + R * 64 + (ph ^ 4) * 8);
        }
        f16x8 bh[3], bl[3];
#pragma unroll
        for (int nt = 0; nt < 3; ++nt) {
            size_t o = ((size_t)(s * G + g0 + nt) * 64 + lane) * 8;
            bh[nt] = *reinterpret_cast<const f16x8*>(Bph + o);
            bl[nt] = *reinterpret_cast<const f16x8*>(Bpl + o);
        }
#pragma unroll
        for (int mt = 0; mt < MT; ++mt)
#pragma unroll
            for (int nt = 0; nt < 3; ++nt) {
                acc[mt][nt] = __builtin_amdgcn_mfma_f32_16x16x32_f16(ah[mt], bh[nt], acc[mt][nt], 0, 0, 0);
                acc2[mt][nt] = __builtin_amdgcn_mfma_f32_16x16x32_f16(ah[mt], bl[nt], acc2[mt][nt], 0, 0, 0);
                acc2[mt][nt] = __builtin_amdgcn_mfma_f32_16x16x32_f16(al[mt], bh[nt], acc2[mt][nt], 0, 0, 0);
            }
    }

    // epilogue: C/D layout col=lane&15, row=quad*4+reg
    float bv[3];
#pragma unroll
    for (int nt = 0; nt < 3; ++nt) bv[nt] = bias ? bias[n0 + nt * 16 + l16] : 0.f;
#pragma unroll
    for (int mt = 0; mt < MT; ++mt)
#pragma unroll
        for (int i = 0; i < 4; ++i) {
            int row = row0 + mt * 16 + quad * 4 + i;
            if (row < M) {
                float rs = rowscale ? rowscale[row] : 1.f;
#pragma unroll
                for (int nt = 0; nt < 3; ++nt) {
                    int col = n0 + nt * 16 + l16;
                    float v = acc[mt][nt][i] + acc2[mt][nt][i] * (1.f / 2048.f) + bv[nt];
                    if (ACT == 1) v = fmaxf(v, 0.f);
                    v *= rs;
                    if (OM & 1) Cf[(size_t)row * NN + col] = v;
                    if (OM & 2) {
                        _Float16 hi = (_Float16)v;
                        _Float16 lo = (_Float16)((v - (float)hi) * 2048.f);
                        int r = row & 31;
                        int os = col >> 5, oc = (col >> 3) & 3, j = col & 7;
                        size_t base = ((size_t)((row >> 5) * NSO + os) * 32 + r) * 64;
                        int ph2 = oc ^ (r & 7);
                        Cp[base + ph2 * 8 + j] = hi;
                        Cp[base + (ph2 ^ 4) * 8 + j] = lo;
                    }
                }
            }
        }
}

// ---------------------------------------------------------------------------
// fp32 whole-row aggregation (r7's verified 94-us design). One wave per
// node, lanes 0..47 x float4 gather from row-major msc; h block-packed.
// ---------------------------------------------------------------------------
__global__ __launch_bounds__(256) void aggregate_kernel(
    const float* __restrict__ msc, const int* __restrict__ csr,
    const int* __restrict__ rowptr, const float* __restrict__ dinv,
    const float* __restrict__ bias, _Float16* __restrict__ h, int M) {
    int wid = (blockIdx.x * 256 + threadIdx.x) >> 6;
    int lane = threadIdx.x & 63;
    if (wid >= M || lane >= 48) return;
    const float4* base = reinterpret_cast<const float4*>(msc);
    float4 a = base[(size_t)wid * 48 + lane];  // self-loop (already * dinv[wid])
    float4 a2 = make_float4(0.f, 0.f, 0.f, 0.f);
    int beg = rowptr[wid], end = rowptr[wid + 1];
    int e = beg;
    for (; e + 1 < end; e += 2) {
        int s0 = csr[e], s1 = csr[e + 1];
        float4 v0 = base[(size_t)s0 * 48 + lane];
        float4 v1 = base[(size_t)s1 * 48 + lane];
        a.x += v0.x; a.y += v0.y; a.z += v0.z; a.w += v0.w;
        a2.x += v1.x; a2.y += v1.y; a2.z += v1.z; a2.w += v1.w;
    }
    if (e < end) {
        int s = csr[e];
        float4 v = base[(size_t)s * 48 + lane];
        a.x += v.x; a.y += v.y; a.z += v.z; a.w += v.w;
    }
    a.x += a2.x; a.y += a2.y; a.z += a2.z; a.w += a2.w;
    float dn = dinv[wid];
    float4 b = reinterpret_cast<const float4*>(bias)[lane];

    // packed-h granule for features f0 = lane*4 .. +4
    int f0 = lane * 4;
    int s = f0 >> 5, c = (f0 >> 3) & 3, jh = (f0 >> 2) & 1;
    int r = wid & 31;
    size_t pbase = ((size_t)((wid >> 5) * 6 + s) * 32 + r) * 64;
    int ph = c ^ (r & 7);
    f16x4* hp = reinterpret_cast<f16x4*>(h + pbase + ph * 8 + jh * 4);
    f16x4* lp = reinterpret_cast<f16x4*>(h + pbase + (ph ^ 4) * 8 + jh * 4);
    f16x4 hh = *hp, hl = *lp;
    float4 hv;
    hv.x = (float)hh[0] + (float)hl[0] * (1.f / 2048.f) + fmaxf(a.x * dn + b.x, 0.f);
    hv.y = (float)hh[1] + (float)hl[1] * (1.f / 2048.f) + fmaxf(a.y * dn + b.y, 0.f);
    hv.z = (float)hh[2] + (float)hl[2] * (1.f / 2048.f) + fmaxf(a.z * dn + b.z, 0.f);
    hv.w = (float)hh[3] + (float)hl[3] * (1.f / 2048.f) + fmaxf(a.w * dn + b.w, 0.f);
    f16x4 nh = {(_Float16)hv.x, (_Float16)hv.y, (_Float16)hv.z, (_Float16)hv.w};
    f16x4 nl = {(_Float16)((hv.x - (float)nh[0]) * 2048.f),
                (_Float16)((hv.y - (float)nh[1]) * 2048.f),
                (_Float16)((hv.z - (float)nh[2]) * 2048.f),
                (_Float16)((hv.w - (float)nh[3]) * 2048.f)};
    *hp = nh;
    *lp = nl;
}

// ---------------------------------------------------------------------------
// Fused tail (direct-load GEMMs): p2 = relu(p1@Wp2+b), r = relu(h@Wr1+b),
// then pos = p2·Wp3+bp3, rad = sigmoid(r·Wr2+br2),
// out = pos/(|pos|+1e-8)*rad. LDS only for result tiles. 32 rows/block.
// Wave w: rows [(w>>1)*16,+16), cols [(w&1)*48,+48).
// ---------------------------------------------------------------------------
__global__ __launch_bounds__(256, 2) void tail_kernel(
    const _Float16* __restrict__ p1p, const _Float16* __restrict__ hp_,
    const _Float16* __restrict__ W2h, const _Float16* __restrict__ W2l,
    const _Float16* __restrict__ Wrh, const _Float16* __restrict__ Wrl,
    const float* __restrict__ bp2, const float* __restrict__ br1,
    const float* __restrict__ Wp3, const float* __restrict__ bp3,
    const float* __restrict__ Wr2, const float* __restrict__ br2,
    float* __restrict__ out, int M) {
    __shared__ float p2t[32 * 96];
    __shared__ float rbt[32 * 96];
    const int tid = threadIdx.x;
    const int wave = tid >> 6, lane = tid & 63;
    const int quad = lane >> 4, l16 = lane & 15;
    const int m0 = (wave >> 1) * 16;
    const int n0 = (wave & 1) * 48;
    const int g0 = n0 >> 4;  // G = 6
    const int row0 = blockIdx.x * 32;

    f32x4 aP[3], aP2[3], aR[3], aR2[3];
#pragma unroll
    for (int nt = 0; nt < 3; ++nt) {
        aP[nt] = (f32x4){0.f, 0.f, 0.f, 0.f};
        aP2[nt] = aP[nt]; aR[nt] = aP[nt]; aR2[nt] = aP[nt];
    }

#pragma unroll
    for (int s = 0; s < 6; ++s) {
        const _Float16* pgP = p1p + ((size_t)blockIdx.x * 6 + s) * 2048;
        const _Float16* pgH = hp_ + ((size_t)blockIdx.x * 6 + s) * 2048;
        int R = m0 + l16;
        int ph = quad ^ (R & 7);
        f16x8 p1h = *reinterpret_cast<const f16x8*>(pgP + R * 64 + ph * 8);
        f16x8 p1l = *reinterpret_cast<const f16x8*>(pgP + R * 64 + (ph ^ 4) * 8);
        f16x8 hh = *reinterpret_cast<const f16x8*>(pgH + R * 64 + ph * 8);
        f16x8 hl = *reinterpret_cast<const f16x8*>(pgH + R * 64 + (ph ^ 4) * 8);
        f16x8 b2h[3], b2l[3], brh[3], brl[3];
#pragma unroll
        for (int nt = 0; nt < 3; ++nt) {
            size_t o = ((size_t)(s * 6 + g0 + nt) * 64 + lane) * 8;
            b2h[nt] = *reinterpret_cast<const f16x8*>(W2h + o);
            b2l[nt] = *reinterpret_cast<const f16x8*>(W2l + o);
            brh[nt] = *reinterpret_cast<const f16x8*>(Wrh + o);
            brl[nt] = *reinterpret_cast<const f16x8*>(Wrl + o);
        }
#pragma unroll
        for (int nt = 0; nt < 3; ++nt) {
            aP[nt] = __builtin_amdgcn_mfma_f32_16x16x32_f16(p1h, b2h[nt], aP[nt], 0, 0, 0);
            aP2[nt] = __builtin_amdgcn_mfma_f32_16x16x32_f16(p1h, b2l[nt], aP2[nt], 0, 0, 0);
            aP2[nt] = __builtin_amdgcn_mfma_f32_16x16x32_f16(p1l, b2h[nt], aP2[nt], 0, 0, 0);
            aR[nt] = __builtin_amdgcn_mfma_f32_16x16x32_f16(hh, brh[nt], aR[nt], 0, 0, 0);
            aR2[nt] = __builtin_amdgcn_mfma_f32_16x16x32_f16(hh, brl[nt], aR2[nt], 0, 0, 0);
            aR2[nt] = __builtin_amdgcn_mfma_f32_16x16x32_f16(hl, brh[nt], aR2[nt], 0, 0, 0);
        }
    }

#pragma unroll
    for (int i = 0; i < 4; ++i) {
        int row = m0 + quad * 4 + i;  // 0..31
#pragma unroll
        for (int nt = 0; nt < 3; ++nt) {
            int col = n0 + nt * 16 + l16;
            float v2 = aP[nt][i] + aP2[nt][i] * (1.f / 2048.f) + bp2[col];
            float vr = aR[nt][i] + aR2[nt][i] * (1.f / 2048.f) + br1[col];
            p2t[row * 96 + col] = fmaxf(v2, 0.f);
            rbt[row * 96 + col] = fmaxf(vr, 0.f);
        }
    }
    __syncthreads();

    if (tid < 32) {
        int row = row0 + tid;
        if (row < M) {
            float a0 = 0.f, a1 = 0.f, rr = 0.f;
            const float* p = p2t + tid * 96;
            const float* r = rbt + tid * 96;
#pragma unroll
            for (int j = 0; j < 96; ++j) {
                a0 += p[j] * Wp3[j * 2 + 0];
                a1 += p[j] * Wp3[j * 2 + 1];
                rr += r[j] * Wr2[j];
            }
            a0 += bp3[0];
            a1 += bp3[1];
            rr += br2[0];
            float radius = 1.f / (1.f + expf(-rr));
            float nrm = sqrtf(a0 * a0 + a1 * a1) + 1e-8f;
            float sc = radius / nrm;
            out[(size_t)row * 2 + 0] = a0 * sc;
            out[(size_t)row * 2 + 1] = a1 * sc;
        }
    }
}

extern "C" void kernel_launch(void* const* d_in, const int* in_sizes, int n_in,
                              void* d_out, int out_size, void* d_ws, size_t ws_size,
                              hipStream_t stream) {
    const float* x     = (const float*)d_in[0];
    const int*   ei    = (const int*)d_in[1];
    const float* Wp    = (const float*)d_in[2];
    const float* bp    = (const float*)d_in[3];
    const float* convW = (const float*)d_in[4];
    const float* convB = (const float*)d_in[5];
    const float* Wp1   = (const float*)d_in[6];
    const float* bp1   = (const float*)d_in[7];
    const float* Wp2   = (const float*)d_in[8];
    const float* bp2   = (const float*)d_in[9];
    const float* Wp3   = (const float*)d_in[10];
    const float* bp3   = (const float*)d_in[11];
    const float* Wr1   = (const float*)d_in[12];
    const float* br1   = (const float*)d_in[13];
    const float* Wr2   = (const float*)d_in[14];
    const float* br2   = (const float*)d_in[15];
    float* out = (float*)d_out;

    const int M = in_sizes[0] / 128;  // 50000
    const int E = in_sizes[1] / 2;    // 800000
    const int* srcI = ei;
    const int* dstI = ei + E;
    const int RBp = (M + 31) / 32;    // 1563 32-row pages / GEMM blocks
    const int Mr  = RBp * 32;

    char* w = (char*)d_ws;
    size_t off = 0;
    auto alloc = [&](size_t b) { size_t o = off; off += (b + 255) & ~(size_t)255; return o; };
    float*    msc  = (float*)(w + alloc((size_t)Mr * 192 * 4));      // row-major fp32; reused as p1 packed
    _Float16* hpk  = (_Float16*)(w + alloc((size_t)RBp * 6 * 4096)); // h packed
    _Float16* xpk  = (_Float16*)(w + alloc((size_t)RBp * 4 * 4096)); // x packed
    _Float16* WpPh  = (_Float16*)(w + alloc((size_t)128 * 192 * 2));
    _Float16* WpPl  = (_Float16*)(w + alloc((size_t)128 * 192 * 2));
    _Float16* cWPh  = (_Float16*)(w + alloc((size_t)4 * 192 * 192 * 2));
    _Float16* cWPl  = (_Float16*)(w + alloc((size_t)4 * 192 * 192 * 2));
    _Float16* Wp1Ph = (_Float16*)(w + alloc((size_t)192 * 192 * 2));
    _Float16* Wp1Pl = (_Float16*)(w + alloc((size_t)192 * 192 * 2));
    _Float16* Wp2Ph = (_Float16*)(w + alloc((size_t)192 * 96 * 2));
    _Float16* Wp2Pl = (_Float16*)(w + alloc((size_t)192 * 96 * 2));
    _Float16* Wr1Ph = (_Float16*)(w + alloc((size_t)192 * 96 * 2));
    _Float16* Wr1Pl = (_Float16*)(w + alloc((size_t)192 * 96 * 2));
    int*      cnt    = (int*)(w + alloc((size_t)M * 4));
    int*      cursor = (int*)(w + alloc((size_t)M * 4));
    float*    dinv   = (float*)(w + alloc((size_t)M * 4));
    int*      rowptr = (int*)(w + alloc((size_t)(M + 1) * 4));
    int*      csr    = (int*)(w + alloc((size_t)(E + 64) * 4));
    int*      bsum   = (int*)(w + alloc(256 * 4));
    int*      boff   = (int*)(w + alloc(256 * 4));

    _Float16* p1pk = (_Float16*)msc;  // alias: msc dead after last aggregate

    hipMemsetAsync(cnt, 0, (size_t)((char*)cursor - (char*)cnt) + (size_t)M * 4, stream);

    // fused prep: count + convert_x + pack_b
    const int xchunks = RBp * 4 * 256;
    const int nCount = (E + 255) / 256;
    const int nConv  = (xchunks + 255) / 256;
    WSegs segs;
    segs.s[0] = {Wp, WpPh, WpPl, 128, 192};
    segs.s[1] = {convW + 0 * 192 * 192, cWPh + 0 * 192 * 192, cWPl + 0 * 192 * 192, 192, 192};
    segs.s[2] = {convW + 1 * 192 * 192, cWPh + 1 * 192 * 192, cWPl + 1 * 192 * 192, 192, 192};
    segs.s[3] = {convW + 2 * 192 * 192, cWPh + 2 * 192 * 192, cWPl + 2 * 192 * 192, 192, 192};
    segs.s[4] = {convW + 3 * 192 * 192, cWPh + 3 * 192 * 192, cWPl + 3 * 192 * 192, 192, 192};
    segs.s[5] = {Wp1, Wp1Ph, Wp1Pl, 192, 192};
    segs.s[6] = {Wp2, Wp2Ph, Wp2Pl, 192, 96};
    segs.s[7] = {Wr1, Wr1Ph, Wr1Pl, 192, 96};
    prep_kernel<<<nCount + nConv + 8 * 144, 256, 0, stream>>>(
        dstI, E, cnt, x, xpk, M, xchunks, segs, nCount, nConv);

    int nb = (M + 255) / 256;
    scan1_kernel<<<nb, 256, 0, stream>>>(cnt, M, rowptr, bsum, dinv);
    scan2_kernel<<<1, 256, 0, stream>>>(bsum, nb, boff);
    scan3_kernel<<<(M + 256) / 256, 256, 0, stream>>>(rowptr, M, E, boff);
    fill_kernel<<<(E + 255) / 256, 256, 0, stream>>>(srcI, dstI, E, rowptr, cursor, csr);

    // h = x @ Wp + bp -> packed planes
    mfma_gemm<128, 192, 0, 2><<<RBp, 256, 0, stream>>>(
        xpk, WpPh, WpPl, bp, nullptr, nullptr, hpk, M);
    // 4 GCN layers: msc = (h@W)*dinv row-major fp32; whole-row aggregate
    for (int i = 0; i < 4; i++) {
        mfma_gemm<192, 192, 0, 1><<<RBp, 256, 0, stream>>>(
            hpk, cWPh + (size_t)i * 192 * 192, cWPl + (size_t)i * 192 * 192,
            nullptr, dinv, msc, nullptr, M);
        aggregate_kernel<<<(M + 3) / 4, 256, 0, stream>>>(
            msc, csr, rowptr, dinv, convB + (size_t)i * 192, hpk, M);
    }
    // p1 = relu(h @ Wp1 + bp1) -> packed (aliases msc)
    mfma_gemm<192, 192, 1, 2><<<RBp, 256, 0, stream>>>(
        hpk, Wp1Ph, Wp1Pl, bp1, nullptr, nullptr, p1pk, M);
    // fused p2/r GEMMs + finalize
    tail_kernel<<<RBp, 256, 0, stream>>>(
        p1pk, hpk, Wp2Ph, Wp2Pl, Wr1Ph, Wr1Pl, bp2, br1,
        Wp3, bp3, Wr2, br2, out, M);
}

// Round 11
// 679.097 us; speedup vs baseline: 1.3746x; 1.0739x over previous
//
#include <hip/hip_runtime.h>
#include <hip/hip_fp8.h>
#include <math.h>

typedef __attribute__((ext_vector_type(8))) _Float16 f16x8;
typedef __attribute__((ext_vector_type(4))) _Float16 f16x4;
typedef __attribute__((ext_vector_type(4))) float f32x4;

// ---------------------------------------------------------------------------
// Precision: GEMMs are split-fp16 (a = ah + al/2048) -> ~2^-22 rel.
// msc (the gathered message buffer) is fp16-hi + fp8-e4m3-lo (x2048) ->
// ~2^-15 rel. Anchor: r2 measured bf16 (4e-3 rel) -> absmax 0.317, i.e.
// effective amplification ~79x through pos/|pos|; 2^-15 -> ~2.5e-3. Budget
// threshold 1.9e-2 -> ~5x margin.
//
// Round 11: msc compression. Whole-program model says we are ~80% of an
// all-fabric-bound limit (~3.7 TB/s L2-fill); msc is the dominant stream
// (write 38.4 MB + 8x-XCD-amplified gather ~270 MB per layer). fp16+fp8
// cuts 6 lines/edge-gather to 5 and write to 28.8 MB.
// GEMM structure frozen from r10 (barrier-free, LDS-free, packed layout).
// Aggregation structure frozen from r7 (whole-row, wave-per-node).
// ---------------------------------------------------------------------------

__device__ __forceinline__ float fp8_to_f32(unsigned char b) {
    __hip_fp8_e4m3 v;
    v.__x = b;
    return static_cast<float>(v);
}
__device__ __forceinline__ unsigned char f32_to_fp8(float x) {
    return __hip_fp8_e4m3(x).__x;
}

// ------------------------- graph setup -------------------------------------
__global__ void scan1_kernel(const int* __restrict__ cnt, int M,
                             int* __restrict__ rowptr, int* __restrict__ bsum,
                             float* __restrict__ dinv) {
    __shared__ int s[256];
    int t = threadIdx.x;
    int i = blockIdx.x * 256 + t;
    int v = (i < M) ? cnt[i] : 0;
    s[t] = v; __syncthreads();
    for (int o = 1; o < 256; o <<= 1) {
        int x = (t >= o) ? s[t - o] : 0;
        __syncthreads();
        s[t] += x;
        __syncthreads();
    }
    if (i < M) {
        rowptr[i] = s[t] - v;
        dinv[i] = rsqrtf((float)v + 1.0f);  // deg = in-deg + self-loop
    }
    if (t == 255) bsum[blockIdx.x] = s[255];
}

__global__ void scan2_kernel(const int* __restrict__ bsum, int nb, int* __restrict__ boff) {
    __shared__ int s[256];
    int t = threadIdx.x;
    int v = (t < nb) ? bsum[t] : 0;
    s[t] = v; __syncthreads();
    for (int o = 1; o < 256; o <<= 1) {
        int x = (t >= o) ? s[t - o] : 0;
        __syncthreads();
        s[t] += x;
        __syncthreads();
    }
    if (t < nb) boff[t] = s[t] - v;
}

__global__ void scan3_kernel(int* __restrict__ rowptr, int M, int E, const int* __restrict__ boff) {
    int i = blockIdx.x * 256 + threadIdx.x;
    if (i < M) rowptr[i] += boff[blockIdx.x];
    if (i == M) rowptr[M] = E;
}

__global__ void fill_kernel(const int* __restrict__ src, const int* __restrict__ dst, int E,
                            const int* __restrict__ rowptr, int* __restrict__ cursor,
                            int* __restrict__ csr) {
    int i = blockIdx.x * blockDim.x + threadIdx.x;
    if (i < E) {
        int d = dst[i];
        int slot = atomicAdd(&cursor[d], 1);
        csr[rowptr[d] + slot] = src[i];
    }
}

// ---------------- fused prep: count + convert_x + pack_b --------------------
struct WSeg { const float* src; _Float16* dh; _Float16* dl; int K; int N; };
struct WSegs { WSeg s[8]; };

__global__ void prep_kernel(const int* __restrict__ dst, int E, int* __restrict__ cnt,
                            const float* __restrict__ x, _Float16* __restrict__ xp,
                            int M, int xchunks, WSegs segs,
                            int nCount, int nConv) {
    int b = blockIdx.x;
    if (b < nCount) {
        int i = b * 256 + threadIdx.x;
        if (i < E) atomicAdd(&cnt[dst[i]], 1);
        return;
    }
    b -= nCount;
    if (b < nConv) {
        // x -> block-packed split planes (4 slabs), one 16-B chunk per thread
        int g = b * 256 + threadIdx.x;
        if (g >= xchunks) return;
        int p = g & 7;
        int t1 = g >> 3;
        int r = t1 & 31;
        int t2 = t1 >> 5;
        int s = t2 & 3;
        int rb = t2 >> 2;
        int c = p ^ (r & 7);
        int node = rb * 32 + r;
        int k = s * 32 + (c & 3) * 8;
        f16x8 o = {};
        if (node < M) {
            const float* xr = x + (size_t)node * 128 + k;
#pragma unroll
            for (int j = 0; j < 8; ++j) {
                float v = xr[j];
                _Float16 hi = (_Float16)v;
                o[j] = (c < 4) ? hi : (_Float16)((v - (float)hi) * 2048.f);
            }
        }
        reinterpret_cast<f16x8*>(xp)[g] = o;
        return;
    }
    b -= nConv;
    // pack_b: frag-major WT planes, flat i = ((s*G+g)*64+l)*8+j
    WSeg sg = segs.s[b / 144];
    int i = (b % 144) * 256 + threadIdx.x;
    if (i >= sg.K * sg.N) return;
    int G = sg.N >> 4;
    int s = i / (G * 512);
    int r = i - s * (G * 512);
    int g = r >> 9;
    int r2 = r & 511;
    int l = r2 >> 3, j = r2 & 7;
    int n = g * 16 + (l & 15);
    int k = s * 32 + (l >> 4) * 8 + j;
    float w = sg.src[(size_t)k * sg.N + n];
    _Float16 hi = (_Float16)w;
    sg.dh[i] = hi;
    sg.dl[i] = (_Float16)((w - (float)hi) * 2048.f);
}

// ---------------------------------------------------------------------------
// Barrier-free LDS-free split-fp16 MFMA GEMM (r10 structure). 256 thr =
// 4 waves, 32 rows/block, wave w -> cols [w*48,+48) (NN=192). Direct
// sector-coalesced global loads; fully unrolled; no s_barrier.
// OM bit0: fp16+fp8 msc out (Ch16 row-major 192, C8 row-major 192).
// OM bit1: block-packed split out Cp. rowscale applied before quantize.
// ---------------------------------------------------------------------------
template <int KK, int NN, int ACT, int OM>
__global__ __launch_bounds__(256, 4) void mfma_gemm(
    const _Float16* __restrict__ Ap,
    const _Float16* __restrict__ Bph, const _Float16* __restrict__ Bpl,
    const float* __restrict__ bias, const float* __restrict__ rowscale,
    _Float16* __restrict__ Ch16, unsigned char* __restrict__ C8,
    _Float16* __restrict__ Cp, int M) {
    constexpr int NS = KK / 32;
    constexpr int G = NN / 16;
    constexpr int MT = 2;
    constexpr int NSO = NN / 32;

    const int tid = threadIdx.x;
    const int wave = tid >> 6, lane = tid & 63;
    const int quad = lane >> 4, l16 = lane & 15;
    const int n0 = wave * 48;
    const int g0 = n0 >> 4;
    const int row0 = blockIdx.x * 32;
    const _Float16* page0 = Ap + (size_t)blockIdx.x * NS * 2048;

    f32x4 acc[MT][3], acc2[MT][3];
#pragma unroll
    for (int mt = 0; mt < MT; ++mt)
#pragma unroll
        for (int nt = 0; nt < 3; ++nt) {
            acc[mt][nt] = (f32x4){0.f, 0.f, 0.f, 0.f};
            acc2[mt][nt] = (f32x4){0.f, 0.f, 0.f, 0.f};
        }

#pragma unroll
    for (int s = 0; s < NS; ++s) {
        const _Float16* pg = page0 + s * 2048;
        f16x8 ah[MT], al[MT];
#pragma unroll
        for (int mt = 0; mt < MT; ++mt) {
            int R = mt * 16 + l16;
            int ph = quad ^ (R & 7);
            ah[mt] = *reinterpret_cast<const f16x8*>(pg + R * 64 + ph * 8);
            al[mt] = *reinterpret_cast<const f16x8*>(pg + R * 64 + (ph ^ 4) * 8);
        }
        f16x8 bh[3], bl[3];
#pragma unroll
        for (int nt = 0; nt < 3; ++nt) {
            size_t o = ((size_t)(s * G + g0 + nt) * 64 + lane) * 8;
            bh[nt] = *reinterpret_cast<const f16x8*>(Bph + o);
            bl[nt] = *reinterpret_cast<const f16x8*>(Bpl + o);
        }
#pragma unroll
        for (int mt = 0; mt < MT; ++mt)
#pragma unroll
            for (int nt = 0; nt < 3; ++nt) {
                acc[mt][nt] = __builtin_amdgcn_mfma_f32_16x16x32_f16(ah[mt], bh[nt], acc[mt][nt], 0, 0, 0);
                acc2[mt][nt] = __builtin_amdgcn_mfma_f32_16x16x32_f16(ah[mt], bl[nt], acc2[mt][nt], 0, 0, 0);
                acc2[mt][nt] = __builtin_amdgcn_mfma_f32_16x16x32_f16(al[mt], bh[nt], acc2[mt][nt], 0, 0, 0);
            }
    }

    // epilogue: C/D layout col=lane&15, row=quad*4+reg
    float bv[3];
#pragma unroll
    for (int nt = 0; nt < 3; ++nt) bv[nt] = bias ? bias[n0 + nt * 16 + l16] : 0.f;
#pragma unroll
    for (int mt = 0; mt < MT; ++mt)
#pragma unroll
        for (int i = 0; i < 4; ++i) {
            int row = row0 + mt * 16 + quad * 4 + i;
            if (row < M) {
                float rs = rowscale ? rowscale[row] : 1.f;
#pragma unroll
                for (int nt = 0; nt < 3; ++nt) {
                    int col = n0 + nt * 16 + l16;
                    float v = acc[mt][nt][i] + acc2[mt][nt][i] * (1.f / 2048.f) + bv[nt];
                    if (ACT == 1) v = fmaxf(v, 0.f);
                    v *= rs;
                    if (OM & 1) {
                        _Float16 hi = (_Float16)v;
                        Ch16[(size_t)row * NN + col] = hi;
                        C8[(size_t)row * NN + col] = f32_to_fp8((v - (float)hi) * 2048.f);
                    }
                    if (OM & 2) {
                        _Float16 hi = (_Float16)v;
                        _Float16 lo = (_Float16)((v - (float)hi) * 2048.f);
                        int r = row & 31;
                        int os = col >> 5, oc = (col >> 3) & 3, j = col & 7;
                        size_t base = ((size_t)((row >> 5) * NSO + os) * 32 + r) * 64;
                        int ph2 = oc ^ (r & 7);
                        Cp[base + ph2 * 8 + j] = hi;
                        Cp[base + (ph2 ^ 4) * 8 + j] = lo;
                    }
                }
            }
        }
}

// ---------------------------------------------------------------------------
// fp16+fp8 whole-row aggregation (r7 structure). One wave per node, lanes
// 0..47: per edge load f16x4 hi (8 B) + uchar4 lo (4 B); separate hi/lo
// fp32 accumulator chains, combined once: sum = hisum + losum/2048.
// h = h + relu(dinv[n]*sum + B); h block-packed split-fp16.
// ---------------------------------------------------------------------------
__global__ __launch_bounds__(256) void aggregate_kernel(
    const _Float16* __restrict__ msch, const unsigned char* __restrict__ mscl,
    const int* __restrict__ csr, const int* __restrict__ rowptr,
    const float* __restrict__ dinv, const float* __restrict__ bias,
    _Float16* __restrict__ h, int M) {
    int wid = (blockIdx.x * 256 + threadIdx.x) >> 6;
    int lane = threadIdx.x & 63;
    if (wid >= M || lane >= 48) return;

    // self-loop term
    f16x4 sh = *reinterpret_cast<const f16x4*>(msch + (size_t)wid * 192 + lane * 4);
    uchar4 sl = *reinterpret_cast<const uchar4*>(mscl + (size_t)wid * 192 + lane * 4);
    float4 ah0 = make_float4((float)sh[0], (float)sh[1], (float)sh[2], (float)sh[3]);
    float4 al0 = make_float4(fp8_to_f32(sl.x), fp8_to_f32(sl.y),
                             fp8_to_f32(sl.z), fp8_to_f32(sl.w));
    float4 ah1 = make_float4(0.f, 0.f, 0.f, 0.f);
    float4 al1 = make_float4(0.f, 0.f, 0.f, 0.f);

    int beg = rowptr[wid], end = rowptr[wid + 1];
    int e = beg;
    for (; e + 1 < end; e += 2) {
        int s0 = csr[e], s1 = csr[e + 1];
        f16x4 h0 = *reinterpret_cast<const f16x4*>(msch + (size_t)s0 * 192 + lane * 4);
        uchar4 l0 = *reinterpret_cast<const uchar4*>(mscl + (size_t)s0 * 192 + lane * 4);
        f16x4 h1 = *reinterpret_cast<const f16x4*>(msch + (size_t)s1 * 192 + lane * 4);
        uchar4 l1 = *reinterpret_cast<const uchar4*>(mscl + (size_t)s1 * 192 + lane * 4);
        ah0.x += (float)h0[0]; ah0.y += (float)h0[1]; ah0.z += (float)h0[2]; ah0.w += (float)h0[3];
        al0.x += fp8_to_f32(l0.x); al0.y += fp8_to_f32(l0.y);
        al0.z += fp8_to_f32(l0.z); al0.w += fp8_to_f32(l0.w);
        ah1.x += (float)h1[0]; ah1.y += (float)h1[1]; ah1.z += (float)h1[2]; ah1.w += (float)h1[3];
        al1.x += fp8_to_f32(l1.x); al1.y += fp8_to_f32(l1.y);
        al1.z += fp8_to_f32(l1.z); al1.w += fp8_to_f32(l1.w);
    }
    if (e < end) {
        int s0 = csr[e];
        f16x4 h0 = *reinterpret_cast<const f16x4*>(msch + (size_t)s0 * 192 + lane * 4);
        uchar4 l0 = *reinterpret_cast<const uchar4*>(mscl + (size_t)s0 * 192 + lane * 4);
        ah0.x += (float)h0[0]; ah0.y += (float)h0[1]; ah0.z += (float)h0[2]; ah0.w += (float)h0[3];
        al0.x += fp8_to_f32(l0.x); al0.y += fp8_to_f32(l0.y);
        al0.z += fp8_to_f32(l0.z); al0.w += fp8_to_f32(l0.w);
    }
    float4 a;
    a.x = (ah0.x + ah1.x) + (al0.x + al1.x) * (1.f / 2048.f);
    a.y = (ah0.y + ah1.y) + (al0.y + al1.y) * (1.f / 2048.f);
    a.z = (ah0.z + ah1.z) + (al0.z + al1.z) * (1.f / 2048.f);
    a.w = (ah0.w + ah1.w) + (al0.w + al1.w) * (1.f / 2048.f);

    float dn = dinv[wid];
    float4 b = reinterpret_cast<const float4*>(bias)[lane];

    // packed-h granule for features f0 = lane*4 .. +4
    int f0 = lane * 4;
    int s = f0 >> 5, c = (f0 >> 3) & 3, jh = (f0 >> 2) & 1;
    int r = wid & 31;
    size_t pbase = ((size_t)((wid >> 5) * 6 + s) * 32 + r) * 64;
    int ph = c ^ (r & 7);
    f16x4* hp = reinterpret_cast<f16x4*>(h + pbase + ph * 8 + jh * 4);
    f16x4* lp = reinterpret_cast<f16x4*>(h + pbase + (ph ^ 4) * 8 + jh * 4);
    f16x4 hh = *hp, hl = *lp;
    float4 hv;
    hv.x = (float)hh[0] + (float)hl[0] * (1.f / 2048.f) + fmaxf(a.x * dn + b.x, 0.f);
    hv.y = (float)hh[1] + (float)hl[1] * (1.f / 2048.f) + fmaxf(a.y * dn + b.y, 0.f);
    hv.z = (float)hh[2] + (float)hl[2] * (1.f / 2048.f) + fmaxf(a.z * dn + b.z, 0.f);
    hv.w = (float)hh[3] + (float)hl[3] * (1.f / 2048.f) + fmaxf(a.w * dn + b.w, 0.f);
    f16x4 nh = {(_Float16)hv.x, (_Float16)hv.y, (_Float16)hv.z, (_Float16)hv.w};
    f16x4 nl = {(_Float16)((hv.x - (float)nh[0]) * 2048.f),
                (_Float16)((hv.y - (float)nh[1]) * 2048.f),
                (_Float16)((hv.z - (float)nh[2]) * 2048.f),
                (_Float16)((hv.w - (float)nh[3]) * 2048.f)};
    *hp = nh;
    *lp = nl;
}

// ---------------------------------------------------------------------------
// Fused tail (r10): p2 = relu(p1@Wp2+b), r = relu(h@Wr1+b) direct-load
// MFMA; then pos = p2·Wp3+bp3, rad = sigmoid(r·Wr2+br2),
// out = pos/(|pos|+1e-8)*rad. 32 rows/block.
// ---------------------------------------------------------------------------
__global__ __launch_bounds__(256, 2) void tail_kernel(
    const _Float16* __restrict__ p1p, const _Float16* __restrict__ hp_,
    const _Float16* __restrict__ W2h, const _Float16* __restrict__ W2l,
    const _Float16* __restrict__ Wrh, const _Float16* __restrict__ Wrl,
    const float* __restrict__ bp2, const float* __restrict__ br1,
    const float* __restrict__ Wp3, const float* __restrict__ bp3,
    const float* __restrict__ Wr2, const float* __restrict__ br2,
    float* __restrict__ out, int M) {
    __shared__ float p2t[32 * 96];
    __shared__ float rbt[32 * 96];
    const int tid = threadIdx.x;
    const int wave = tid >> 6, lane = tid & 63;
    const int quad = lane >> 4, l16 = lane & 15;
    const int m0 = (wave >> 1) * 16;
    const int n0 = (wave & 1) * 48;
    const int g0 = n0 >> 4;  // G = 6
    const int row0 = blockIdx.x * 32;

    f32x4 aP[3], aP2[3], aR[3], aR2[3];
#pragma unroll
    for (int nt = 0; nt < 3; ++nt) {
        aP[nt] = (f32x4){0.f, 0.f, 0.f, 0.f};
        aP2[nt] = aP[nt]; aR[nt] = aP[nt]; aR2[nt] = aP[nt];
    }

#pragma unroll
    for (int s = 0; s < 6; ++s) {
        const _Float16* pgP = p1p + ((size_t)blockIdx.x * 6 + s) * 2048;
        const _Float16* pgH = hp_ + ((size_t)blockIdx.x * 6 + s) * 2048;
        int R = m0 + l16;
        int ph = quad ^ (R & 7);
        f16x8 p1h = *reinterpret_cast<const f16x8*>(pgP + R * 64 + ph * 8);
        f16x8 p1l = *reinterpret_cast<const f16x8*>(pgP + R * 64 + (ph ^ 4) * 8);
        f16x8 hh = *reinterpret_cast<const f16x8*>(pgH + R * 64 + ph * 8);
        f16x8 hl = *reinterpret_cast<const f16x8*>(pgH + R * 64 + (ph ^ 4) * 8);
        f16x8 b2h[3], b2l[3], brh[3], brl[3];
#pragma unroll
        for (int nt = 0; nt < 3; ++nt) {
            size_t o = ((size_t)(s * 6 + g0 + nt) * 64 + lane) * 8;
            b2h[nt] = *reinterpret_cast<const f16x8*>(W2h + o);
            b2l[nt] = *reinterpret_cast<const f16x8*>(W2l + o);
            brh[nt] = *reinterpret_cast<const f16x8*>(Wrh + o);
            brl[nt] = *reinterpret_cast<const f16x8*>(Wrl + o);
        }
#pragma unroll
        for (int nt = 0; nt < 3; ++nt) {
            aP[nt] = __builtin_amdgcn_mfma_f32_16x16x32_f16(p1h, b2h[nt], aP[nt], 0, 0, 0);
            aP2[nt] = __builtin_amdgcn_mfma_f32_16x16x32_f16(p1h, b2l[nt], aP2[nt], 0, 0, 0);
            aP2[nt] = __builtin_amdgcn_mfma_f32_16x16x32_f16(p1l, b2h[nt], aP2[nt], 0, 0, 0);
            aR[nt] = __builtin_amdgcn_mfma_f32_16x16x32_f16(hh, brh[nt], aR[nt], 0, 0, 0);
            aR2[nt] = __builtin_amdgcn_mfma_f32_16x16x32_f16(hh, brl[nt], aR2[nt], 0, 0, 0);
            aR2[nt] = __builtin_amdgcn_mfma_f32_16x16x32_f16(hl, brh[nt], aR2[nt], 0, 0, 0);
        }
    }

#pragma unroll
    for (int i = 0; i < 4; ++i) {
        int row = m0 + quad * 4 + i;  // 0..31
#pragma unroll
        for (int nt = 0; nt < 3; ++nt) {
            int col = n0 + nt * 16 + l16;
            float v2 = aP[nt][i] + aP2[nt][i] * (1.f / 2048.f) + bp2[col];
            float vr = aR[nt][i] + aR2[nt][i] * (1.f / 2048.f) + br1[col];
            p2t[row * 96 + col] = fmaxf(v2, 0.f);
            rbt[row * 96 + col] = fmaxf(vr, 0.f);
        }
    }
    __syncthreads();

    if (tid < 32) {
        int row = row0 + tid;
        if (row < M) {
            float a0 = 0.f, a1 = 0.f, rr = 0.f;
            const float* p = p2t + tid * 96;
            const float* r = rbt + tid * 96;
#pragma unroll
            for (int j = 0; j < 96; ++j) {
                a0 += p[j] * Wp3[j * 2 + 0];
                a1 += p[j] * Wp3[j * 2 + 1];
                rr += r[j] * Wr2[j];
            }
            a0 += bp3[0];
            a1 += bp3[1];
            rr += br2[0];
            float radius = 1.f / (1.f + expf(-rr));
            float nrm = sqrtf(a0 * a0 + a1 * a1) + 1e-8f;
            float sc = radius / nrm;
            out[(size_t)row * 2 + 0] = a0 * sc;
            out[(size_t)row * 2 + 1] = a1 * sc;
        }
    }
}

extern "C" void kernel_launch(void* const* d_in, const int* in_sizes, int n_in,
                              void* d_out, int out_size, void* d_ws, size_t ws_size,
                              hipStream_t stream) {
    const float* x     = (const float*)d_in[0];
    const int*   ei    = (const int*)d_in[1];
    const float* Wp    = (const float*)d_in[2];
    const float* bp    = (const float*)d_in[3];
    const float* convW = (const float*)d_in[4];
    const float* convB = (const float*)d_in[5];
    const float* Wp1   = (const float*)d_in[6];
    const float* bp1   = (const float*)d_in[7];
    const float* Wp2   = (const float*)d_in[8];
    const float* bp2   = (const float*)d_in[9];
    const float* Wp3   = (const float*)d_in[10];
    const float* bp3   = (const float*)d_in[11];
    const float* Wr1   = (const float*)d_in[12];
    const float* br1   = (const float*)d_in[13];
    const float* Wr2   = (const float*)d_in[14];
    const float* br2   = (const float*)d_in[15];
    float* out = (float*)d_out;

    const int M = in_sizes[0] / 128;  // 50000
    const int E = in_sizes[1] / 2;    // 800000
    const int* srcI = ei;
    const int* dstI = ei + E;
    const int RBp = (M + 31) / 32;    // 1563 32-row pages / GEMM blocks
    const int Mr  = RBp * 32;

    char* w = (char*)d_ws;
    size_t off = 0;
    auto alloc = [&](size_t b) { size_t o = off; off += (b + 255) & ~(size_t)255; return o; };
    // msc region also hosts p1 packed later (38.4 MB >= 19.2+9.6)
    char*     mscreg = w + alloc((size_t)RBp * 6 * 4096);
    _Float16* hpk  = (_Float16*)(w + alloc((size_t)RBp * 6 * 4096)); // h packed
    _Float16* xpk  = (_Float16*)(w + alloc((size_t)RBp * 4 * 4096)); // x packed
    _Float16* WpPh  = (_Float16*)(w + alloc((size_t)128 * 192 * 2));
    _Float16* WpPl  = (_Float16*)(w + alloc((size_t)128 * 192 * 2));
    _Float16* cWPh  = (_Float16*)(w + alloc((size_t)4 * 192 * 192 * 2));
    _Float16* cWPl  = (_Float16*)(w + alloc((size_t)4 * 192 * 192 * 2));
    _Float16* Wp1Ph = (_Float16*)(w + alloc((size_t)192 * 192 * 2));
    _Float16* Wp1Pl = (_Float16*)(w + alloc((size_t)192 * 192 * 2));
    _Float16* Wp2Ph = (_Float16*)(w + alloc((size_t)192 * 96 * 2));
    _Float16* Wp2Pl = (_Float16*)(w + alloc((size_t)192 * 96 * 2));
    _Float16* Wr1Ph = (_Float16*)(w + alloc((size_t)192 * 96 * 2));
    _Float16* Wr1Pl = (_Float16*)(w + alloc((size_t)192 * 96 * 2));
    int*      cnt    = (int*)(w + alloc((size_t)M * 4));
    int*      cursor = (int*)(w + alloc((size_t)M * 4));
    float*    dinv   = (float*)(w + alloc((size_t)M * 4));
    int*      rowptr = (int*)(w + alloc((size_t)(M + 1) * 4));
    int*      csr    = (int*)(w + alloc((size_t)(E + 64) * 4));
    int*      bsum   = (int*)(w + alloc(256 * 4));
    int*      boff   = (int*)(w + alloc(256 * 4));

    _Float16*      msch = (_Float16*)mscreg;                       // 19.2 MB
    unsigned char* mscl = (unsigned char*)(mscreg + (size_t)Mr * 192 * 2);  // 9.6 MB
    _Float16*      p1pk = (_Float16*)mscreg;  // alias: msc dead after last aggregate

    hipMemsetAsync(cnt, 0, (size_t)((char*)cursor - (char*)cnt) + (size_t)M * 4, stream);

    // fused prep: count + convert_x + pack_b
    const int xchunks = RBp * 4 * 256;
    const int nCount = (E + 255) / 256;
    const int nConv  = (xchunks + 255) / 256;
    WSegs segs;
    segs.s[0] = {Wp, WpPh, WpPl, 128, 192};
    segs.s[1] = {convW + 0 * 192 * 192, cWPh + 0 * 192 * 192, cWPl + 0 * 192 * 192, 192, 192};
    segs.s[2] = {convW + 1 * 192 * 192, cWPh + 1 * 192 * 192, cWPl + 1 * 192 * 192, 192, 192};
    segs.s[3] = {convW + 2 * 192 * 192, cWPh + 2 * 192 * 192, cWPl + 2 * 192 * 192, 192, 192};
    segs.s[4] = {convW + 3 * 192 * 192, cWPh + 3 * 192 * 192, cWPl + 3 * 192 * 192, 192, 192};
    segs.s[5] = {Wp1, Wp1Ph, Wp1Pl, 192, 192};
    segs.s[6] = {Wp2, Wp2Ph, Wp2Pl, 192, 96};
    segs.s[7] = {Wr1, Wr1Ph, Wr1Pl, 192, 96};
    prep_kernel<<<nCount + nConv + 8 * 144, 256, 0, stream>>>(
        dstI, E, cnt, x, xpk, M, xchunks, segs, nCount, nConv);

    int nb = (M + 255) / 256;
    scan1_kernel<<<nb, 256, 0, stream>>>(cnt, M, rowptr, bsum, dinv);
    scan2_kernel<<<1, 256, 0, stream>>>(bsum, nb, boff);
    scan3_kernel<<<(M + 256) / 256, 256, 0, stream>>>(rowptr, M, E, boff);
    fill_kernel<<<(E + 255) / 256, 256, 0, stream>>>(srcI, dstI, E, rowptr, cursor, csr);

    // h = x @ Wp + bp -> packed planes
    mfma_gemm<128, 192, 0, 2><<<RBp, 256, 0, stream>>>(
        xpk, WpPh, WpPl, bp, nullptr, nullptr, nullptr, hpk, M);
    // 4 GCN layers: msc = (h@W)*dinv -> fp16+fp8 planes; whole-row aggregate
    for (int i = 0; i < 4; i++) {
        mfma_gemm<192, 192, 0, 1><<<RBp, 256, 0, stream>>>(
            hpk, cWPh + (size_t)i * 192 * 192, cWPl + (size_t)i * 192 * 192,
            nullptr, dinv, msch, mscl, nullptr, M);
        aggregate_kernel<<<(M + 3) / 4, 256, 0, stream>>>(
            msch, mscl, csr, rowptr, dinv, convB + (size_t)i * 192, hpk, M);
    }
    // p1 = relu(h @ Wp1 + bp1) -> packed (aliases msc region)
    mfma_gemm<192, 192, 1, 2><<<RBp, 256, 0, stream>>>(
        hpk, Wp1Ph, Wp1Pl, bp1, nullptr, nullptr, nullptr, p1pk, M);
    // fused p2/r GEMMs + finalize
    tail_kernel<<<RBp, 256, 0, stream>>>(
        p1pk, hpk, Wp2Ph, Wp2Pl, Wr1Ph, Wr1Pl, bp2, br1,
        Wp3, bp3, Wr2, br2, out, M);
}